// Round 1
// baseline (198.724 us; speedup 1.0000x reference)
//
#include <hip/hip_runtime.h>
#include <hip/hip_bf16.h>
#include <math.h>

// GAT: B=4, N=2048, in=128, out=32, heads=4
// outputs: H_new [4,2048,128] f32 (1048576) then alpha [4,4,2048,2048] f32 (67108864)

typedef float f32x4 __attribute__((ext_vector_type(4)));
typedef short bf16x8 __attribute__((ext_vector_type(8)));

#define LRELU 0.2f

__device__ inline ushort f2b(float x) {
    unsigned int u = __float_as_uint(x);
    u += 0x7fffu + ((u >> 16) & 1u);   // RNE
    return (ushort)(u >> 16);
}

// ---------------- k1: Ht = H @ W[h], src/dst dots, write Ht^T as bf16 [bh][f][k] -----------
__global__ __launch_bounds__(256) void k1_ht(const float* __restrict__ H,
                                             const float* __restrict__ W,
                                             const float* __restrict__ a,
                                             __hip_bfloat16* __restrict__ HtT,
                                             float* __restrict__ src,
                                             float* __restrict__ dst) {
    __shared__ float Ws[128 * 32];      // 16 KB
    __shared__ float Hs[8 * 128];       // 4 KB
    __shared__ float T[32 * 9];         // transpose buffer, padded

    int t = threadIdx.x;
    int g0 = blockIdx.x * 8;            // first global row id in [0, 32768)
    int bh = g0 >> 11;
    int n0 = g0 & 2047;
    int b = bh >> 2, h = bh & 3;

    #pragma unroll
    for (int u = 0; u < 16; ++u) Ws[u * 256 + t] = W[h * 4096 + u * 256 + t];
    #pragma unroll
    for (int u = 0; u < 4; ++u) {
        int s = u * 256 + t;
        int r = s >> 7, i = s & 127;
        Hs[s] = H[(size_t)(b * 2048 + n0 + r) * 128 + i];
    }
    __syncthreads();

    int r = t >> 5, f = t & 31;
    float acc = 0.f;
    #pragma unroll
    for (int i = 0; i < 128; ++i) acc += Hs[r * 128 + i] * Ws[i * 32 + f];

    float sv = acc * a[h * 64 + f];
    float dv = acc * a[h * 64 + 32 + f];
    #pragma unroll
    for (int off = 16; off; off >>= 1) {
        sv += __shfl_xor(sv, off);
        dv += __shfl_xor(dv, off);
    }
    if (f == 0) { src[g0 + r] = sv; dst[g0 + r] = dv; }

    T[f * 9 + r] = acc;
    __syncthreads();
    if (t < 128) {
        int fp = t >> 2, p = t & 3;
        __hip_bfloat162 v2;
        v2.x = __float2bfloat16(T[fp * 9 + 2 * p]);
        v2.y = __float2bfloat16(T[fp * 9 + 2 * p + 1]);
        *(__hip_bfloat162*)&HtT[(size_t)(bh * 32 + fp) * 2048 + n0 + 2 * p] = v2;
    }
}

// ---------------- k2: per (bh,n) row softmax -> alpha (fp32, output) ----------------------
__global__ __launch_bounds__(256) void k2_alpha(const float* __restrict__ adj,
                                                const float* __restrict__ src,
                                                const float* __restrict__ dst,
                                                float* __restrict__ alpha) {
    int bh = blockIdx.x;     // 16
    int n  = blockIdx.y;     // 2048
    int t = threadIdx.x;
    int lane = t & 63, wid = t >> 6;
    __shared__ float wmax[4], wsum[4];

    float sn = src[bh * 2048 + n];
    const float4* adj4 = (const float4*)adj + (size_t)n * 512;
    const float4* dst4 = (const float4*)dst + (size_t)bh * 512;

    float e[8];
    #pragma unroll
    for (int c = 0; c < 2; ++c) {
        int j4 = c * 256 + t;
        float4 av = adj4[j4];
        float4 dv = dst4[j4];
        int jb = j4 * 4;
        float aj[4] = {av.x, av.y, av.z, av.w};
        float dj[4] = {dv.x, dv.y, dv.z, dv.w};
        #pragma unroll
        for (int q = 0; q < 4; ++q) {
            float ee = sn + dj[q];
            ee = (ee >= 0.f) ? ee : LRELU * ee;
            bool m = (aj[q] != 0.f) || (jb + q == n);
            e[c * 4 + q] = m ? ee : -1e30f;
        }
    }

    float M = -1e30f;
    #pragma unroll
    for (int q = 0; q < 8; ++q) M = fmaxf(M, e[q]);
    #pragma unroll
    for (int off = 32; off; off >>= 1) M = fmaxf(M, __shfl_xor(M, off));
    if (lane == 0) wmax[wid] = M;
    __syncthreads();
    M = fmaxf(fmaxf(wmax[0], wmax[1]), fmaxf(wmax[2], wmax[3]));

    float p[8];
    float S = 0.f;
    #pragma unroll
    for (int q = 0; q < 8; ++q) { p[q] = __expf(e[q] - M); S += p[q]; }
    #pragma unroll
    for (int off = 32; off; off >>= 1) S += __shfl_xor(S, off);
    if (lane == 0) wsum[wid] = S;
    __syncthreads();
    S = (wsum[0] + wsum[1]) + (wsum[2] + wsum[3]);
    float inv = 1.f / S;

    float4* out4 = (float4*)alpha + (size_t)(bh * 2048 + n) * 512;
    #pragma unroll
    for (int c = 0; c < 2; ++c) {
        float4 o;
        o.x = p[c * 4 + 0] * inv;
        o.y = p[c * 4 + 1] * inv;
        o.z = p[c * 4 + 2] * inv;
        o.w = p[c * 4 + 3] * inv;
        out4[c * 256 + t] = o;
    }
}

// ---------------- k3: H_new = ELU(alpha @ Ht) via bf16 MFMA -------------------------------
// block: 256 thr (4 waves). tile M=64 (rows), N=32 (all cols), BK=128.
__global__ __launch_bounds__(256) void k3_gemm(const float* __restrict__ alpha,
                                               const __hip_bfloat16* __restrict__ HtT,
                                               float* __restrict__ outH) {
    __shared__ __align__(16) ushort As[64 * 128];   // 16 KB, XOR-swizzled [row][k]
    __shared__ __align__(16) ushort Bs[32 * 128];   // 8 KB,  XOR-swizzled [n][k]

    int t = threadIdx.x;
    int mtile = blockIdx.x;   // 32
    int bh = blockIdx.y;      // 16
    int lane = t & 63, w = t >> 6;
    int b = bh >> 2, h = bh & 3;
    int l15 = lane & 15, l4 = lane >> 4;

    f32x4 acc0 = {0.f, 0.f, 0.f, 0.f};
    f32x4 acc1 = {0.f, 0.f, 0.f, 0.f};

    const float* Abase = alpha + (size_t)(bh * 2048 + mtile * 64) * 2048;
    const ushort* Bbase = (const ushort*)HtT + (size_t)bh * 32 * 2048;

    for (int k0 = 0; k0 < 2048; k0 += 128) {
        // stage A: 64x128 fp32 -> bf16 swizzled
        #pragma unroll
        for (int u = 0; u < 8; ++u) {
            int s = u * 256 + t;            // 2048 float4 slots
            int row = s >> 5, c4 = s & 31;
            float4 v = *(const float4*)(Abase + (size_t)row * 2048 + k0 + c4 * 4);
            ushort4 bv;
            bv.x = f2b(v.x); bv.y = f2b(v.y); bv.z = f2b(v.z); bv.w = f2b(v.w);
            int idx = (row * 128 + c4 * 4) ^ ((row & 7) << 3);
            *(ushort4*)&As[idx] = bv;
        }
        // stage B: 32x128 bf16 (already transposed in ws) swizzled
        #pragma unroll
        for (int u = 0; u < 2; ++u) {
            int s = u * 256 + t;            // 512 short8 slots
            int nr = s >> 4, c8 = s & 15;
            uint4 v = *(const uint4*)(Bbase + (size_t)nr * 2048 + k0 + c8 * 8);
            int idx = (nr * 128 + c8 * 8) ^ ((nr & 7) << 3);
            *(uint4*)&Bs[idx] = v;
        }
        __syncthreads();

        int arow = w * 16 + l15;
        #pragma unroll
        for (int kk = 0; kk < 4; ++kk) {
            int colk = kk * 32 + l4 * 8;
            bf16x8 av  = *(const bf16x8*)&As[(arow * 128 + colk) ^ ((arow & 7) << 3)];
            bf16x8 bv0 = *(const bf16x8*)&Bs[(l15 * 128 + colk) ^ ((l15 & 7) << 3)];
            bf16x8 bv1 = *(const bf16x8*)&Bs[((16 + l15) * 128 + colk) ^ ((l15 & 7) << 3)];
            acc0 = __builtin_amdgcn_mfma_f32_16x16x32_bf16(av, bv0, acc0, 0, 0, 0);
            acc1 = __builtin_amdgcn_mfma_f32_16x16x32_bf16(av, bv1, acc1, 0, 0, 0);
        }
        __syncthreads();
    }

    // epilogue: ELU + write H_new[b][node][h*32+col]
    #pragma unroll
    for (int nf = 0; nf < 2; ++nf) {
        f32x4 acc = nf ? acc1 : acc0;
        int col = nf * 16 + l15;
        #pragma unroll
        for (int q = 0; q < 4; ++q) {
            int node = mtile * 64 + w * 16 + l4 * 4 + q;
            float v = acc[q];
            v = (v > 0.f) ? v : expm1f(v);
            outH[(size_t)(b * 2048 + node) * 128 + h * 32 + col] = v;
        }
    }
}

extern "C" void kernel_launch(void* const* d_in, const int* in_sizes, int n_in,
                              void* d_out, int out_size, void* d_ws, size_t ws_size,
                              hipStream_t stream) {
    const float* H   = (const float*)d_in[0];
    const float* adj = (const float*)d_in[1];
    const float* W   = (const float*)d_in[2];
    const float* a   = (const float*)d_in[3];

    float* outH  = (float*)d_out;
    float* alpha = outH + (size_t)4 * 2048 * 128;   // 1048576

    char* ws = (char*)d_ws;
    __hip_bfloat16* HtT = (__hip_bfloat16*)ws;                 // 16*32*2048 bf16 = 2 MB
    float* src = (float*)(ws + 2 * 1024 * 1024);               // 32768 f32
    float* dst = src + 32768;                                  // 32768 f32

    k1_ht<<<4096, 256, 0, stream>>>(H, W, a, HtT, src, dst);
    k2_alpha<<<dim3(16, 2048), 256, 0, stream>>>(adj, src, dst, alpha);
    k3_gemm<<<dim3(32, 16), 256, 0, stream>>>(alpha, HtT, outH);
}

// Round 3
// 93.301 us; speedup vs baseline: 2.1299x; 2.1299x over previous
//
#include <hip/hip_runtime.h>
#include <hip/hip_bf16.h>
#include <math.h>

// GAT: B=4, N=2048, in=128, out=32, heads=4
// outputs: H_new [4,2048,128] f32 (1048576) then alpha [4,4,2048,2048] f32 (67108864)

typedef float f32x4 __attribute__((ext_vector_type(4)));
typedef short bf16x8 __attribute__((ext_vector_type(8)));

#define LRELU 0.2f

__device__ inline ushort f2b(float x) {
    unsigned int u = __float_as_uint(x);
    u += 0x7fffu + ((u >> 16) & 1u);   // RNE
    return (ushort)(u >> 16);
}

// ---------------- k1: Ht = H @ W[h], src/dst dots, write Ht^T as bf16 [bh][f][k] -----------
__global__ __launch_bounds__(256) void k1_ht(const float* __restrict__ H,
                                             const float* __restrict__ W,
                                             const float* __restrict__ a,
                                             __hip_bfloat16* __restrict__ HtT,
                                             float* __restrict__ src,
                                             float* __restrict__ dst) {
    __shared__ float Ws[128 * 32];      // 16 KB
    __shared__ float Hs[8 * 128];       // 4 KB
    __shared__ float T[32 * 9];         // transpose buffer, padded

    int t = threadIdx.x;
    int g0 = blockIdx.x * 8;            // first global row id in [0, 32768)
    int bh = g0 >> 11;
    int n0 = g0 & 2047;
    int b = bh >> 2, h = bh & 3;

    #pragma unroll
    for (int u = 0; u < 16; ++u) Ws[u * 256 + t] = W[h * 4096 + u * 256 + t];
    #pragma unroll
    for (int u = 0; u < 4; ++u) {
        int s = u * 256 + t;
        int r = s >> 7, i = s & 127;
        Hs[s] = H[(size_t)(b * 2048 + n0 + r) * 128 + i];
    }
    __syncthreads();

    int r = t >> 5, f = t & 31;
    float acc = 0.f;
    #pragma unroll
    for (int i = 0; i < 128; ++i) acc += Hs[r * 128 + i] * Ws[i * 32 + f];

    float sv = acc * a[h * 64 + f];
    float dv = acc * a[h * 64 + 32 + f];
    #pragma unroll
    for (int off = 16; off; off >>= 1) {
        sv += __shfl_xor(sv, off);
        dv += __shfl_xor(dv, off);
    }
    if (f == 0) { src[g0 + r] = sv; dst[g0 + r] = dv; }

    T[f * 9 + r] = acc;
    __syncthreads();
    if (t < 128) {
        int fp = t >> 2, p = t & 3;
        __hip_bfloat162 v2;
        v2.x = __float2bfloat16(T[fp * 9 + 2 * p]);
        v2.y = __float2bfloat16(T[fp * 9 + 2 * p + 1]);
        *(__hip_bfloat162*)&HtT[(size_t)(bh * 32 + fp) * 2048 + n0 + 2 * p] = v2;
    }
}

// ---------------- fused: softmax stats -> alpha (nt-store) -> MFMA -> ELU -> H_new ---------
// grid (64 mtiles of 32 rows, 16 bh), block 256 (4 waves).
__global__ __launch_bounds__(256) void k2_fused(const float* __restrict__ adj,
                                                const float* __restrict__ src,
                                                const float* __restrict__ dst,
                                                const __hip_bfloat16* __restrict__ HtT,
                                                float* __restrict__ alpha,
                                                float* __restrict__ outH) {
    __shared__ float dstS[2048];                     // 8 KB
    __shared__ float rowM[32], rowInvS[32], rowSrc[32];
    __shared__ __align__(16) ushort As[32 * 128];    // 8 KB, XOR-swizzled alpha tile (bf16)
    __shared__ __align__(16) ushort Bs[32 * 128];    // 8 KB, XOR-swizzled HtT tile

    int t = threadIdx.x;
    int mtile = blockIdx.x;   // 64
    int bh    = blockIdx.y;   // 16
    int lane = t & 63, w = t >> 6;
    int b = bh >> 2, h = bh & 3;
    int row0 = mtile * 32;

    // stage dst row-vector (2048 floats) and the 32 src scalars
    const float4* dst4g = (const float4*)(dst + bh * 2048);
    #pragma unroll
    for (int u = 0; u < 2; ++u) {
        float4 v = dst4g[u * 256 + t];
        *(float4*)&dstS[(u * 256 + t) * 4] = v;
    }
    if (t < 32) rowSrc[t] = src[bh * 2048 + row0 + t];
    __syncthreads();

    // ---- pass A: per-row max & sum over full 2048 row ----
    // wave w handles rows w*8 .. w*8+7
    for (int rr = 0; rr < 8; ++rr) {
        int r = w * 8 + rr;
        int gr = row0 + r;
        float sn = rowSrc[r];
        const float4* adj4 = (const float4*)(adj + (size_t)gr * 2048);
        float e[32];
        #pragma unroll
        for (int u = 0; u < 8; ++u) {
            float4 av = adj4[u * 64 + lane];
            int jb = (u * 64 + lane) * 4;
            float aj[4] = {av.x, av.y, av.z, av.w};
            #pragma unroll
            for (int q = 0; q < 4; ++q) {
                float ee = sn + dstS[jb + q];
                ee = (ee >= 0.f) ? ee : LRELU * ee;
                bool m = (aj[q] != 0.f) || (jb + q == gr);
                e[u * 4 + q] = m ? ee : -1e30f;
            }
        }
        float M = e[0];
        #pragma unroll
        for (int q = 1; q < 32; ++q) M = fmaxf(M, e[q]);
        #pragma unroll
        for (int off = 32; off; off >>= 1) M = fmaxf(M, __shfl_xor(M, off));
        float S = 0.f;
        #pragma unroll
        for (int q = 0; q < 32; ++q) S += __expf(e[q] - M);
        #pragma unroll
        for (int off = 32; off; off >>= 1) S += __shfl_xor(S, off);
        if (lane == 0) { rowM[r] = M; rowInvS[r] = 1.f / S; }
    }
    __syncthreads();

    // ---- pass B: per 128-wide K-chunk: alpha tile -> nt-store + LDS; MFMA ----
    f32x4 acc = {0.f, 0.f, 0.f, 0.f};
    int wr = w >> 1, wc = w & 1;
    int l15 = lane & 15, l4 = lane >> 4;
    const ushort* Bbase = (const ushort*)HtT + (size_t)bh * 32 * 2048;
    float* alphaRow = alpha + (size_t)(bh * 2048 + row0) * 2048;

    for (int k0 = 0; k0 < 2048; k0 += 128) {
        // alpha tile: 32 rows x 128 cols = 1024 float4 slots
        #pragma unroll
        for (int u = 0; u < 4; ++u) {
            int s = u * 256 + t;
            int r = s >> 5, c4 = s & 31;
            int gr = row0 + r;
            int jb = k0 + c4 * 4;
            float4 av = *(const float4*)(adj + (size_t)gr * 2048 + jb);
            float sn = rowSrc[r], M = rowM[r], invS = rowInvS[r];
            float aj[4] = {av.x, av.y, av.z, av.w};
            float o[4];
            #pragma unroll
            for (int q = 0; q < 4; ++q) {
                float ee = sn + dstS[jb + q];
                ee = (ee >= 0.f) ? ee : LRELU * ee;
                bool m = (aj[q] != 0.f) || (jb + q == gr);
                ee = m ? ee : -1e30f;
                o[q] = __expf(ee - M) * invS;
            }
            f32x4 ov = {o[0], o[1], o[2], o[3]};
            __builtin_nontemporal_store(ov, (f32x4*)(alphaRow + (size_t)r * 2048 + jb));
            ushort4 bv;
            bv.x = f2b(o[0]); bv.y = f2b(o[1]); bv.z = f2b(o[2]); bv.w = f2b(o[3]);
            int idx = (r * 128 + c4 * 4) ^ ((r & 7) << 3);
            *(ushort4*)&As[idx] = bv;
        }
        // B tile: 32 x 128 bf16 = 512 short8 slots
        #pragma unroll
        for (int u = 0; u < 2; ++u) {
            int s = u * 256 + t;
            int nr = s >> 4, c8 = s & 15;
            uint4 v = *(const uint4*)(Bbase + (size_t)nr * 2048 + k0 + c8 * 8);
            int idx = (nr * 128 + c8 * 8) ^ ((nr & 7) << 3);
            *(uint4*)&Bs[idx] = v;
        }
        __syncthreads();

        int arow = wr * 16 + l15;
        int bcol = wc * 16 + l15;
        #pragma unroll
        for (int kk = 0; kk < 4; ++kk) {
            int colk = kk * 32 + l4 * 8;
            bf16x8 avf = *(const bf16x8*)&As[(arow * 128 + colk) ^ ((arow & 7) << 3)];
            bf16x8 bvf = *(const bf16x8*)&Bs[(bcol * 128 + colk) ^ ((bcol & 7) << 3)];
            acc = __builtin_amdgcn_mfma_f32_16x16x32_bf16(avf, bvf, acc, 0, 0, 0);
        }
        __syncthreads();
    }

    // epilogue: ELU + write H_new[b][node][h*32 + col]
    #pragma unroll
    for (int q = 0; q < 4; ++q) {
        int node = row0 + wr * 16 + l4 * 4 + q;
        float v = acc[q];
        v = (v > 0.f) ? v : expm1f(v);
        outH[(size_t)(b * 2048 + node) * 128 + h * 32 + wc * 16 + l15] = v;
    }
}

extern "C" void kernel_launch(void* const* d_in, const int* in_sizes, int n_in,
                              void* d_out, int out_size, void* d_ws, size_t ws_size,
                              hipStream_t stream) {
    const float* H   = (const float*)d_in[0];
    const float* adj = (const float*)d_in[1];
    const float* W   = (const float*)d_in[2];
    const float* a   = (const float*)d_in[3];

    float* outH  = (float*)d_out;
    float* alpha = outH + (size_t)4 * 2048 * 128;   // 1048576

    char* ws = (char*)d_ws;
    __hip_bfloat16* HtT = (__hip_bfloat16*)ws;                 // 16*32*2048 bf16 = 2 MB
    float* src = (float*)(ws + 2 * 1024 * 1024);               // 32768 f32
    float* dst = src + 32768;                                  // 32768 f32

    k1_ht<<<4096, 256, 0, stream>>>(H, W, a, HtT, src, dst);
    k2_fused<<<dim3(64, 16), 256, 0, stream>>>(adj, src, dst, HtT, alpha, outH);
}

// Round 5
// 89.259 us; speedup vs baseline: 2.2264x; 1.0453x over previous
//
#include <hip/hip_runtime.h>
#include <hip/hip_bf16.h>
#include <math.h>

// GAT: B=4, N=2048, in=128, out=32, heads=4
// outputs: H_new [4,2048,128] f32 (1048576) then alpha [4,4,2048,2048] f32 (67108864)

typedef float f32x4 __attribute__((ext_vector_type(4)));
typedef short bf16x8 __attribute__((ext_vector_type(8)));

#define LRELU 0.2f
#define LOG2E 1.44269504088896f
#define EXP2(x) __builtin_amdgcn_exp2f(x)

__device__ inline ushort f2b(float x) {
    unsigned int u = __float_as_uint(x);
    u += 0x7fffu + ((u >> 16) & 1u);   // RNE
    return (ushort)(u >> 16);
}

// ---------------- k1: Ht = H @ W[h], src/dst dots, write Ht^T as bf16 [bh][f][k] -----------
__global__ __launch_bounds__(256) void k1_ht(const float* __restrict__ H,
                                             const float* __restrict__ W,
                                             const float* __restrict__ a,
                                             __hip_bfloat16* __restrict__ HtT,
                                             float* __restrict__ src,
                                             float* __restrict__ dst) {
    __shared__ float Ws[128 * 32];      // 16 KB
    __shared__ float Hs[8 * 128];       // 4 KB
    __shared__ float T[32 * 9];         // transpose buffer, padded

    int t = threadIdx.x;
    int g0 = blockIdx.x * 8;            // first global row id in [0, 32768)
    int bh = g0 >> 11;
    int n0 = g0 & 2047;
    int b = bh >> 2, h = bh & 3;

    #pragma unroll
    for (int u = 0; u < 16; ++u) Ws[u * 256 + t] = W[h * 4096 + u * 256 + t];
    #pragma unroll
    for (int u = 0; u < 4; ++u) {
        int s = u * 256 + t;
        int r = s >> 7, i = s & 127;
        Hs[s] = H[(size_t)(b * 2048 + n0 + r) * 128 + i];
    }
    __syncthreads();

    int r = t >> 5, f = t & 31;
    float acc = 0.f;
    #pragma unroll
    for (int i = 0; i < 128; ++i) acc += Hs[r * 128 + i] * Ws[i * 32 + f];

    float sv = acc * a[h * 64 + f];
    float dv = acc * a[h * 64 + 32 + f];
    #pragma unroll
    for (int off = 16; off; off >>= 1) {
        sv += __shfl_xor(sv, off);
        dv += __shfl_xor(dv, off);
    }
    if (f == 0) { src[g0 + r] = sv; dst[g0 + r] = dv; }

    T[f * 9 + r] = acc;
    __syncthreads();
    if (t < 128) {
        int fp = t >> 2, p = t & 3;
        __hip_bfloat162 v2;
        v2.x = __float2bfloat16(T[fp * 9 + 2 * p]);
        v2.y = __float2bfloat16(T[fp * 9 + 2 * p + 1]);
        *(__hip_bfloat162*)&HtT[(size_t)(bh * 32 + fp) * 2048 + n0 + 2 * p] = v2;
    }
}

// ---------------- fused: no-max softmax -> alpha (nt-store) -> MFMA -> ELU -> H_new --------
// grid (64 mtiles of 32 rows, 16 bh), block 256 (4 waves).
// Barriers in the K-loop are lgkmcnt-only (LDS deps only) so the nt-store
// stream and global loads are never drained mid-loop.
__global__ __launch_bounds__(256) void k2_fused(const float* __restrict__ adj,
                                                const float* __restrict__ src,
                                                const float* __restrict__ dst,
                                                const __hip_bfloat16* __restrict__ HtT,
                                                float* __restrict__ alpha,
                                                float* __restrict__ outH) {
    __shared__ float dstS[2048];                        // 8 KB (pre-scaled by LOG2E)
    __shared__ float rowInvS[32], rowSrcS[32];
    __shared__ __align__(16) ushort As[2][32 * 128];    // 16 KB dbuf, XOR-swizzled
    __shared__ __align__(16) ushort Bs[2][32 * 128];    // 16 KB dbuf, XOR-swizzled

    int t = threadIdx.x;
    int mtile = blockIdx.x;   // 64
    int bh    = blockIdx.y;   // 16
    int lane = t & 63, w = t >> 6;
    int b = bh >> 2, h = bh & 3;
    int row0 = mtile * 32;

    const float4* dst4g = (const float4*)(dst + bh * 2048);
    #pragma unroll
    for (int u = 0; u < 2; ++u) {
        float4 v = dst4g[u * 256 + t];
        v.x *= LOG2E; v.y *= LOG2E; v.z *= LOG2E; v.w *= LOG2E;
        *(float4*)&dstS[(u * 256 + t) * 4] = v;
    }
    if (t < 32) rowSrcS[t] = src[bh * 2048 + row0 + t] * LOG2E;
    __syncthreads();

    // ---- pass A: per-row sum of exp2 (no max needed: |e| bounded, masked -> 0) ----
    for (int rr = 0; rr < 8; ++rr) {
        int r = w * 8 + rr;
        int gr = row0 + r;
        float sn = rowSrcS[r];
        const float4* adj4 = (const float4*)(adj + (size_t)gr * 2048);
        float S = 0.f;
        #pragma unroll
        for (int u = 0; u < 8; ++u) {
            float4 av = adj4[u * 64 + lane];
            int jb = (u * 64 + lane) * 4;
            float4 dv = *(const float4*)&dstS[jb];
            float aj[4] = {av.x, av.y, av.z, av.w};
            float dj[4] = {dv.x, dv.y, dv.z, dv.w};
            #pragma unroll
            for (int q = 0; q < 4; ++q) {
                float ee = sn + dj[q];
                ee = (ee >= 0.f) ? ee : LRELU * ee;
                bool m = (aj[q] != 0.f) || (jb + q == gr);
                S += m ? EXP2(ee) : 0.f;
            }
        }
        #pragma unroll
        for (int off = 32; off; off >>= 1) S += __shfl_xor(S, off);
        if (lane == 0) rowInvS[r] = 1.f / S;
    }
    __syncthreads();

    // ---- pass B: dbuf pipeline, one lgkm-only barrier per 128-wide K-chunk ----
    f32x4 acc = {0.f, 0.f, 0.f, 0.f};
    int wr = w >> 1, wc = w & 1;
    int l15 = lane & 15, l4 = lane >> 4;
    const ushort* Bbase = (const ushort*)HtT + (size_t)bh * 32 * 2048;
    float* alphaRow = alpha + (size_t)(bh * 2048 + row0) * 2048;

    // per-thread fixed coords for staging
    int sr = t >> 5;            // rows sr, sr+8, sr+16, sr+24 across u
    int sc4 = t & 31;
    int bnr = t >> 4;           // rows bnr, bnr+16
    int bc8 = t & 15;

    auto stage_compute = [&](int k0, const float4* avr, const uint4* bvr,
                             ushort* Asb, ushort* Bsb) {
        #pragma unroll
        for (int u = 0; u < 4; ++u) {
            int r = sr + u * 8;
            int gr = row0 + r;
            int jb = k0 + sc4 * 4;
            float4 av = avr[u];
            float4 dv = *(const float4*)&dstS[jb];
            float sn = rowSrcS[r], invS = rowInvS[r];
            float aj[4] = {av.x, av.y, av.z, av.w};
            float dj[4] = {dv.x, dv.y, dv.z, dv.w};
            float o[4];
            #pragma unroll
            for (int q = 0; q < 4; ++q) {
                float ee = sn + dj[q];
                ee = (ee >= 0.f) ? ee : LRELU * ee;
                bool m = (aj[q] != 0.f) || (jb + q == gr);
                float p = m ? EXP2(ee) : 0.f;
                o[q] = p * invS;
            }
            f32x4 ov = {o[0], o[1], o[2], o[3]};
            __builtin_nontemporal_store(ov, (f32x4*)(alphaRow + (size_t)r * 2048 + jb));
            ushort4 bv;
            bv.x = f2b(o[0]); bv.y = f2b(o[1]); bv.z = f2b(o[2]); bv.w = f2b(o[3]);
            *(ushort4*)&Asb[(r * 128 + sc4 * 4) ^ ((r & 7) << 3)] = bv;
        }
        #pragma unroll
        for (int u = 0; u < 2; ++u) {
            int nr = bnr + u * 16;
            *(uint4*)&Bsb[(nr * 128 + bc8 * 8) ^ ((nr & 7) << 3)] = bvr[u];
        }
    };

    // prologue: load + stage chunk 0
    {
        float4 avr[4]; uint4 bvr[2];
        #pragma unroll
        for (int u = 0; u < 4; ++u)
            avr[u] = *(const float4*)(adj + (size_t)(row0 + sr + u * 8) * 2048 + sc4 * 4);
        #pragma unroll
        for (int u = 0; u < 2; ++u)
            bvr[u] = *(const uint4*)(Bbase + (size_t)(bnr + u * 16) * 2048 + bc8 * 8);
        stage_compute(0, avr, bvr, As[0], Bs[0]);
    }

    for (int kc = 0; kc < 16; ++kc) {
        asm volatile("s_waitcnt lgkmcnt(0)" ::: "memory");
        __builtin_amdgcn_s_barrier();

        // issue next chunk's global loads early (hide under MFMA)
        float4 avr[4]; uint4 bvr[2];
        int kn = (kc + 1) * 128;
        if (kc < 15) {
            #pragma unroll
            for (int u = 0; u < 4; ++u)
                avr[u] = *(const float4*)(adj + (size_t)(row0 + sr + u * 8) * 2048 + kn + sc4 * 4);
            #pragma unroll
            for (int u = 0; u < 2; ++u)
                bvr[u] = *(const uint4*)(Bbase + (size_t)(bnr + u * 16) * 2048 + kn + bc8 * 8);
        }

        const ushort* Asb = As[kc & 1];
        const ushort* Bsb = Bs[kc & 1];
        int arow = wr * 16 + l15;
        int bcol = wc * 16 + l15;
        #pragma unroll
        for (int kk = 0; kk < 4; ++kk) {
            int colk = kk * 32 + l4 * 8;
            bf16x8 avf = *(const bf16x8*)&Asb[(arow * 128 + colk) ^ ((arow & 7) << 3)];
            bf16x8 bvf = *(const bf16x8*)&Bsb[(bcol * 128 + colk) ^ ((bcol & 7) << 3)];
            acc = __builtin_amdgcn_mfma_f32_16x16x32_bf16(avf, bvf, acc, 0, 0, 0);
        }

        if (kc < 15) stage_compute(kn, avr, bvr, As[(kc + 1) & 1], Bs[(kc + 1) & 1]);
    }

    // epilogue: ELU + write H_new[b][node][h*32 + col]
    #pragma unroll
    for (int q = 0; q < 4; ++q) {
        int node = row0 + wr * 16 + l4 * 4 + q;
        float v = acc[q];
        v = (v > 0.f) ? v : expm1f(v);
        outH[(size_t)(b * 2048 + node) * 128 + h * 32 + wc * 16 + l15] = v;
    }
}

extern "C" void kernel_launch(void* const* d_in, const int* in_sizes, int n_in,
                              void* d_out, int out_size, void* d_ws, size_t ws_size,
                              hipStream_t stream) {
    const float* H   = (const float*)d_in[0];
    const float* adj = (const float*)d_in[1];
    const float* W   = (const float*)d_in[2];
    const float* a   = (const float*)d_in[3];

    float* outH  = (float*)d_out;
    float* alpha = outH + (size_t)4 * 2048 * 128;   // 1048576

    char* ws = (char*)d_ws;
    __hip_bfloat16* HtT = (__hip_bfloat16*)ws;                 // 16*32*2048 bf16 = 2 MB
    float* src = (float*)(ws + 2 * 1024 * 1024);               // 32768 f32
    float* dst = src + 32768;                                  // 32768 f32

    k1_ht<<<4096, 256, 0, stream>>>(H, W, a, HtT, src, dst);
    k2_fused<<<dim3(64, 16), 256, 0, stream>>>(adj, src, dst, HtT, alpha, outH);
}